// Round 1
// baseline (361.969 us; speedup 1.0000x reference)
//
#include <hip/hip_runtime.h>

#define NSUBJ 64
#define CIN   295
#define DD    270
#define TT    2048
#define BB    128
#define MPAD  288   // 270 padded to 18*16
#define KPAD  320   // 295 padded to 10*32

typedef __attribute__((ext_vector_type(8))) short bf16x8;
typedef __attribute__((ext_vector_type(4))) float f32x4;

__device__ __forceinline__ unsigned short f2bf(float f) {
    union { float f; unsigned int u; } v; v.f = f;
    unsigned int r = v.u + 0x7FFFu + ((v.u >> 16) & 1u);  // RNE
    return (unsigned short)(r >> 16);
}

// ---------------------------------------------------------------------------
// Kernel 1: Wf[s] = Ws[s] @ W1, f32 compute, bf16 store, zero-padded
// grid (KPAD/64=5, MPAD/96=3, 64), block 256 (16x16), thread tile 6x4, BK=16
// ---------------------------------------------------------------------------
__global__ __launch_bounds__(256) void k_fuse_w(const float* __restrict__ Ws,
                                                const float* __restrict__ W1,
                                                unsigned short* __restrict__ Wf)
{
    __shared__ float As[16][97];   // [kk][m], pad 97 -> conflict-free
    __shared__ float Bs[16][65];   // [kk][n]
    const int tid = threadIdx.x;
    const int tx = tid & 15, ty = tid >> 4;
    const int s  = blockIdx.z;
    const int e0 = blockIdx.y * 96;
    const int n0 = blockIdx.x * 64;
    const float* Wsb = Ws + (size_t)s * DD * DD;

    float acc[6][4];
#pragma unroll
    for (int i = 0; i < 6; ++i)
#pragma unroll
        for (int j = 0; j < 4; ++j) acc[i][j] = 0.f;

    for (int ks = 0; ks < 17; ++ks) {        // 17*16 = 272 >= 270
        const int k0 = ks * 16;
#pragma unroll
        for (int idx = tid; idx < 96 * 16; idx += 256) {
            const int m = idx >> 4, kk = idx & 15;
            const int e = e0 + m, d = k0 + kk;
            As[kk][m] = (e < DD && d < DD) ? Wsb[(size_t)e * DD + d] : 0.f;
        }
#pragma unroll
        for (int idx = tid; idx < 16 * 64; idx += 256) {
            const int kk = idx >> 6, n = idx & 63;
            const int d = k0 + kk, c = n0 + n;
            Bs[kk][n] = (d < DD && c < CIN) ? W1[(size_t)d * CIN + c] : 0.f;
        }
        __syncthreads();
#pragma unroll
        for (int kk = 0; kk < 16; ++kk) {
            float a[6], b[4];
#pragma unroll
            for (int i = 0; i < 6; ++i) a[i] = As[kk][ty * 6 + i];
#pragma unroll
            for (int j = 0; j < 4; ++j) b[j] = Bs[kk][tx * 4 + j];
#pragma unroll
            for (int i = 0; i < 6; ++i)
#pragma unroll
                for (int j = 0; j < 4; ++j) acc[i][j] = fmaf(a[i], b[j], acc[i][j]);
        }
        __syncthreads();
    }
#pragma unroll
    for (int i = 0; i < 6; ++i) {
        const int e = e0 + ty * 6 + i;
#pragma unroll
        for (int j = 0; j < 4; ++j) {
            const int c = n0 + tx * 4 + j;
            Wf[((size_t)s * MPAD + e) * KPAD + c] = f2bf(acc[i][j]);
        }
    }
}

// ---------------------------------------------------------------------------
// Kernel 2: bf[s][e] = sum_d Ws[s][e][d] * b1[d]   (f32, padded rows = 0)
// ---------------------------------------------------------------------------
__global__ __launch_bounds__(256) void k_fuse_b(const float* __restrict__ Ws,
                                                const float* __restrict__ b1,
                                                float* __restrict__ bfv)
{
    const int gid = blockIdx.x * 256 + threadIdx.x;
    if (gid >= NSUBJ * MPAD) return;
    const int s = gid / MPAD, e = gid - s * MPAD;
    float acc = 0.f;
    if (e < DD) {
        const float* row = Ws + ((size_t)s * DD + e) * DD;
        for (int d = 0; d < DD; ++d) acc = fmaf(row[d], b1[d], acc);
    }
    bfv[gid] = acc;
}

// ---------------------------------------------------------------------------
// Kernel 3: out[b] = Wf[subj[b]] @ X[b] + bf[subj[b]]
// grid (3, 16, 128) m-fastest for X L2/L3 reuse; block 512 = 8 waves (2M x 4N)
// BM=96 BN=128 BK=32; mfma_f32_16x16x32_bf16, 3x2 frags per wave
// ---------------------------------------------------------------------------
__global__ __launch_bounds__(512) void k_main(const float* __restrict__ X,
                                              const int* __restrict__ subj,
                                              const unsigned short* __restrict__ Wf,
                                              const float* __restrict__ bfv,
                                              float* __restrict__ out)
{
    __shared__ unsigned short Al[96 * 40];    // [row][kk], row stride 40 el = 80B
    __shared__ unsigned short Bl[128 * 40];   // [n][kk] (X transposed)
    const int tid  = threadIdx.x;
    const int lane = tid & 63;
    const int wid  = tid >> 6;
    const int wm = wid >> 2, wn = wid & 3;    // wave tile: 48 rows x 32 cols
    const int mt = blockIdx.x, nt = blockIdx.y, b = blockIdx.z;
    const int e0 = mt * 96, t0 = nt * 128;
    const int s  = subj[b];
    const float* Xb = X + (size_t)b * CIN * TT;
    const unsigned short* Wfs = Wf + ((size_t)s * MPAD + e0) * KPAD;

    // staging assignments: one 8-element (16B) chunk per thread
    const int arow = tid >> 2;                // 0..127 (A uses <96 -> tid<384)
    const int akq  = (tid & 3) * 8;
    const int xn   = tid >> 2;                // 0..127
    const int xkq  = (tid & 3) * 8;

    f32x4 acc[3][2];
#pragma unroll
    for (int i = 0; i < 3; ++i)
#pragma unroll
        for (int j = 0; j < 2; ++j) acc[i][j] = (f32x4){0.f, 0.f, 0.f, 0.f};

    for (int ks = 0; ks < 10; ++ks) {
        const int k0 = ks * 32;
        // ---- stage A tile (96 x 32 bf16): already padded/bf16 in ws ----
        if (tid < 384) {
            const uint4 v = *(const uint4*)(Wfs + (size_t)arow * KPAD + k0 + akq);
            *(uint4*)(&Al[arow * 40 + akq]) = v;
        }
        // ---- stage X tile transposed: Bl[n][kk] = bf16(X[k0+kk][t0+n]) ----
        {
            unsigned short h[8];
#pragma unroll
            for (int q = 0; q < 8; ++q) {
                const int c = k0 + xkq + q;
                const float v = (c < CIN) ? Xb[(size_t)c * TT + t0 + xn] : 0.f;
                h[q] = f2bf(v);
            }
            *(uint4*)(&Bl[xn * 40 + xkq]) = *(const uint4*)h;
        }
        __syncthreads();
        bf16x8 af[3], bfr[2];
#pragma unroll
        for (int i = 0; i < 3; ++i)
            af[i] = *(const bf16x8*)(&Al[(wm * 48 + i * 16 + (lane & 15)) * 40 + (lane >> 4) * 8]);
#pragma unroll
        for (int j = 0; j < 2; ++j)
            bfr[j] = *(const bf16x8*)(&Bl[(wn * 32 + j * 16 + (lane & 15)) * 40 + (lane >> 4) * 8]);
#pragma unroll
        for (int i = 0; i < 3; ++i)
#pragma unroll
            for (int j = 0; j < 2; ++j)
                acc[i][j] = __builtin_amdgcn_mfma_f32_16x16x32_bf16(af[i], bfr[j], acc[i][j], 0, 0, 0);
        __syncthreads();
    }

    // epilogue: C/D layout col=lane&15, row=(lane>>4)*4+reg  [verified m89/m91]
    const int rb = (lane >> 4) * 4;
    const int cc = lane & 15;
#pragma unroll
    for (int i = 0; i < 3; ++i) {
#pragma unroll
        for (int r = 0; r < 4; ++r) {
            const int e = e0 + wm * 48 + i * 16 + rb + r;
            if (e < DD) {
                const float bias = bfv[s * MPAD + e];
#pragma unroll
                for (int j = 0; j < 2; ++j) {
                    const int t = t0 + wn * 32 + j * 16 + cc;
                    out[((size_t)b * DD + e) * TT + t] = acc[i][j][r] + bias;
                }
            }
        }
    }
}

extern "C" void kernel_launch(void* const* d_in, const int* in_sizes, int n_in,
                              void* d_out, int out_size, void* d_ws, size_t ws_size,
                              hipStream_t stream) {
    const float* X    = (const float*)d_in[0];
    const int*   subj = (const int*)d_in[1];
    const float* W1   = (const float*)d_in[2];
    const float* b1   = (const float*)d_in[3];
    const float* Ws   = (const float*)d_in[4];
    float* out = (float*)d_out;

    unsigned short* Wf = (unsigned short*)d_ws;                       // 64*288*320*2 = 11,796,480 B
    float* bfv = (float*)((char*)d_ws + (size_t)NSUBJ * MPAD * KPAD * 2); // + 73,728 B

    k_fuse_w<<<dim3(KPAD / 64, MPAD / 96, NSUBJ), 256, 0, stream>>>(Ws, W1, Wf);
    k_fuse_b<<<dim3((NSUBJ * MPAD + 255) / 256), 256, 0, stream>>>(Ws, b1, bfv);
    k_main<<<dim3(3, 16, BB), 512, 0, stream>>>(X, subj, Wf, bfv, out);
}

// Round 2
// 350.834 us; speedup vs baseline: 1.0317x; 1.0317x over previous
//
#include <hip/hip_runtime.h>

#define NSUBJ 64
#define CIN   295
#define DD    270
#define TT    2048
#define BB    128

// Wf tiled layout: [s][ks:10][kq:4][m:288][k8:8]  (bf16, c = ks*32+kq*8+k8)
#define WF_PER_S  92160   // 10*4*288*8
#define WF_PER_KS 9216    // 4*288*8
#define WF_PER_KQ 2304    // 288*8
// W1t tiled layout: [nt:5][ks:9][kq:4][n:64][k8:8] (bf16, d = ks*32+kq*8+k8, c = nt*64+n)
#define W1T_PER_NT 18432  // 9*4*64*8
#define W1T_PER_KS 2048
#define W1T_PER_KQ 512

typedef __attribute__((ext_vector_type(8))) short bf16x8;
typedef __attribute__((ext_vector_type(4))) float f32x4;
typedef unsigned short u16;

__device__ __forceinline__ u16 f2bf(float f) {
    union { float f; unsigned int u; } v; v.f = f;
    unsigned int r = v.u + 0x7FFFu + ((v.u >> 16) & 1u);  // RNE
    return (u16)(r >> 16);
}

// async global->LDS: per-lane 16B from g, lands at (uniform lds base) + lane*16
__device__ __forceinline__ void glds16(const u16* g, u16* lds_base) {
    __builtin_amdgcn_global_load_lds(
        (const __attribute__((address_space(1))) unsigned int*)g,
        (__attribute__((address_space(3))) unsigned int*)lds_base, 16, 0, 0);
}

// ---------------------------------------------------------------------------
// W1 [270][295] f32 -> W1t bf16 tiled [nt][ks][kq][n][k8], zero-padded
// ---------------------------------------------------------------------------
__global__ __launch_bounds__(256) void k_prep_w1(const float* __restrict__ W1,
                                                 u16* __restrict__ W1t)
{
    const int idx = blockIdx.x * 256 + threadIdx.x;      // 92160 total
    const int nt = idx / W1T_PER_NT;
    const int r0 = idx - nt * W1T_PER_NT;
    const int ks = r0 / W1T_PER_KS;
    const int r1 = r0 - ks * W1T_PER_KS;
    const int kq = r1 >> 9;
    const int n  = (r1 >> 3) & 63;
    const int k8 = r1 & 7;
    const int d = ks * 32 + kq * 8 + k8;
    const int c = nt * 64 + n;
    W1t[idx] = (d < DD && c < CIN) ? f2bf(W1[d * CIN + c]) : (u16)0;
}

// ---------------------------------------------------------------------------
// bfv[s][e] = dot(Ws[s][e][:], b1)  — one wave per row, shuffle reduce
// ---------------------------------------------------------------------------
__global__ __launch_bounds__(256) void k_fuse_b(const float* __restrict__ Ws,
                                                const float* __restrict__ b1,
                                                float* __restrict__ bfv)
{
    const int s = blockIdx.x;
    const int lane = threadIdx.x & 63, w = threadIdx.x >> 6;
    const float* Wsb = Ws + (size_t)s * DD * DD;
    for (int e = w; e < DD; e += 4) {
        float a = 0.f;
        for (int d = lane; d < DD; d += 64) a = fmaf(Wsb[e * DD + d], b1[d], a);
#pragma unroll
        for (int m = 32; m; m >>= 1) a += __shfl_xor(a, m);
        if (lane == 0) bfv[s * 288 + e] = a;
    }
}

// ---------------------------------------------------------------------------
// Wf[s] = bf16(Ws[s] @ W1), MFMA, output in k_main's tiled A layout
// grid (5 nt, 3 mt, 64 s), block 256 = 4 waves (2M x 2N), tile 96e x 64c, K=288
// ---------------------------------------------------------------------------
__global__ __launch_bounds__(256) void k_fuse_w(const float* __restrict__ Ws,
                                                const u16* __restrict__ W1t,
                                                u16* __restrict__ Wf)
{
    __shared__ u16 Aw[3072];   // [kq:4][96][8]
    __shared__ u16 Bw[2048];   // [kq:4][64][8]
    const int tid = threadIdx.x, lane = tid & 63, wid = tid >> 6;
    const int wm = wid >> 1, wn = wid & 1;
    const int nt = blockIdx.x, mt = blockIdx.y, s = blockIdx.z;
    const int e0 = mt * 96, n0 = nt * 64;
    const float* Wsb = Ws + (size_t)s * DD * DD;

    f32x4 acc[3][2];
#pragma unroll
    for (int i = 0; i < 3; ++i)
#pragma unroll
        for (int j = 0; j < 2; ++j) acc[i][j] = (f32x4){0.f, 0.f, 0.f, 0.f};

    for (int ks = 0; ks < 9; ++ks) {
        const int k0 = ks * 32;
        // A stage: 96x32 f32 -> bf16, 768 4-elem chunks, 3 per thread
#pragma unroll
        for (int ci = 0; ci < 3; ++ci) {
            const int id = tid + ci * 256;
            const int m = id >> 3, q = id & 7;
            const int e = e0 + m, d = k0 + q * 4;
            float2 v01 = {0.f, 0.f}, v23 = {0.f, 0.f};
            if (e < DD) {
                if (d < DD)     v01 = *(const float2*)(Wsb + (size_t)e * DD + d);
                if (d + 2 < DD) v23 = *(const float2*)(Wsb + (size_t)e * DD + d + 2);
            }
            ushort4 h;
            h.x = f2bf(v01.x); h.y = f2bf(v01.y); h.z = f2bf(v23.x); h.w = f2bf(v23.y);
            *(ushort4*)(&Aw[(q >> 1) * 768 + m * 8 + (q & 1) * 4]) = h;
        }
        // B stage: flat 4KB copy from W1t (already tiled/padded)
        glds16(W1t + nt * W1T_PER_NT + ks * W1T_PER_KS + wid * 512 + lane * 8,
               &Bw[wid * 512]);
        __syncthreads();
        bf16x8 bfr[2];
#pragma unroll
        for (int j = 0; j < 2; ++j)
            bfr[j] = *(const bf16x8*)(&Bw[(lane >> 4) * 512 + (wn * 32 + j * 16 + (lane & 15)) * 8]);
#pragma unroll
        for (int i = 0; i < 3; ++i) {
            const bf16x8 af = *(const bf16x8*)(&Aw[(lane >> 4) * 768 + (wm * 48 + i * 16 + (lane & 15)) * 8]);
            acc[i][0] = __builtin_amdgcn_mfma_f32_16x16x32_bf16(af, bfr[0], acc[i][0], 0, 0, 0);
            acc[i][1] = __builtin_amdgcn_mfma_f32_16x16x32_bf16(af, bfr[1], acc[i][1], 0, 0, 0);
        }
        __syncthreads();
    }
    const int rb = (lane >> 4) * 4, cc = lane & 15;
#pragma unroll
    for (int i = 0; i < 3; ++i) {
#pragma unroll
        for (int r = 0; r < 4; ++r) {
            const int e = e0 + wm * 48 + i * 16 + rb + r;
#pragma unroll
            for (int j = 0; j < 2; ++j) {
                const int c = n0 + wn * 32 + j * 16 + cc;
                Wf[(size_t)s * WF_PER_S + (c >> 5) * WF_PER_KS + ((c >> 3) & 3) * WF_PER_KQ
                   + e * 8 + (c & 7)] = f2bf(acc[i][j][r]);
            }
        }
    }
}

// ---------------------------------------------------------------------------
// out[b] = Wf[subj[b]] @ X[b] + bfv[subj[b]]
// grid (32 nt, 128 b), block 256 = 4 waves (2M x 2N), tile 288e x 64t, K=320
// double-buffered LDS, 1 barrier/K-step; A via global_load_lds, B reg-staged
// ---------------------------------------------------------------------------
__global__ __launch_bounds__(256, 2) void k_main(const float* __restrict__ X,
                                                 const int* __restrict__ subj,
                                                 const u16* __restrict__ Wf,
                                                 const float* __restrict__ bfv,
                                                 float* __restrict__ out)
{
    __shared__ u16 Am[2][9216];   // [kq:4][288][8]
    __shared__ u16 Bm[2][2048];   // [kq:4][64][8]
    const int tid = threadIdx.x, lane = tid & 63, wid = tid >> 6;
    const int wm = wid >> 1, wn = wid & 1;
    const int nt = blockIdx.x, b = blockIdx.y;
    const int t0 = nt * 64;
    const int s = subj[b];
    const float* Xb = X + (size_t)b * CIN * TT;
    const u16* WfA = Wf + (size_t)s * WF_PER_S;
    const int bn = tid & 63, bkq = tid >> 6;

    f32x4 acc[9][2];
#pragma unroll
    for (int i = 0; i < 9; ++i)
#pragma unroll
        for (int j = 0; j < 2; ++j) acc[i][j] = (f32x4){0.f, 0.f, 0.f, 0.f};

    float xr[8];
#define LOADB(KS)                                                           \
    {                                                                       \
        _Pragma("unroll")                                                   \
        for (int q = 0; q < 8; ++q) {                                       \
            const int c = (KS) * 32 + bkq * 8 + q;                          \
            xr[q] = (c < CIN) ? Xb[(size_t)c * TT + t0 + bn] : 0.f;         \
        }                                                                   \
    }
#define WRITEB(BUF)                                                         \
    {                                                                       \
        bf16x8 h;                                                           \
        _Pragma("unroll")                                                   \
        for (int q = 0; q < 8; ++q) h[q] = (short)f2bf(xr[q]);              \
        *(bf16x8*)(&Bm[BUF][bkq * 512 + bn * 8]) = h;                       \
    }
#define STAGEA(KS, BUF)                                                     \
    for (int seg = wid; seg < 18; seg += 4)                                 \
        glds16(WfA + (KS) * WF_PER_KS + seg * 512 + lane * 8,               \
               &Am[BUF][seg * 512]);

    // prologue: tile 0
    LOADB(0); STAGEA(0, 0); WRITEB(0);
    __syncthreads();

    int cur = 0;
    for (int ks = 0; ks < 10; ++ks) {
        const int nxt = cur ^ 1;
        if (ks < 9) { LOADB(ks + 1); STAGEA(ks + 1, nxt); }
        bf16x8 bfr[2];
#pragma unroll
        for (int j = 0; j < 2; ++j)
            bfr[j] = *(const bf16x8*)(&Bm[cur][(lane >> 4) * 512 + (wn * 32 + j * 16 + (lane & 15)) * 8]);
#pragma unroll
        for (int i = 0; i < 9; ++i) {
            const bf16x8 af = *(const bf16x8*)(&Am[cur][(lane >> 4) * 2304 + (wm * 144 + i * 16 + (lane & 15)) * 8]);
            acc[i][0] = __builtin_amdgcn_mfma_f32_16x16x32_bf16(af, bfr[0], acc[i][0], 0, 0, 0);
            acc[i][1] = __builtin_amdgcn_mfma_f32_16x16x32_bf16(af, bfr[1], acc[i][1], 0, 0, 0);
        }
        if (ks < 9) WRITEB(nxt);
        __syncthreads();
        cur = nxt;
    }

    // epilogue: C/D layout col=lane&15, row=(lane>>4)*4+reg
    const int rb = (lane >> 4) * 4, cc = lane & 15;
#pragma unroll
    for (int i = 0; i < 9; ++i) {
#pragma unroll
        for (int r = 0; r < 4; ++r) {
            const int e = wm * 144 + i * 16 + rb + r;
            if (e < DD) {
                const float bias = bfv[s * 288 + e];
#pragma unroll
                for (int j = 0; j < 2; ++j) {
                    const int t = t0 + wn * 32 + j * 16 + cc;
                    out[((size_t)b * DD + e) * TT + t] = acc[i][j][r] + bias;
                }
            }
        }
    }
#undef LOADB
#undef WRITEB
#undef STAGEA
}

extern "C" void kernel_launch(void* const* d_in, const int* in_sizes, int n_in,
                              void* d_out, int out_size, void* d_ws, size_t ws_size,
                              hipStream_t stream) {
    const float* X    = (const float*)d_in[0];
    const int*   subj = (const int*)d_in[1];
    const float* W1   = (const float*)d_in[2];
    const float* b1   = (const float*)d_in[3];
    const float* Ws   = (const float*)d_in[4];
    float* out = (float*)d_out;

    u16* Wf  = (u16*)d_ws;                                            // 64*92160*2 = 11,796,480 B
    u16* W1t = (u16*)((char*)d_ws + (size_t)NSUBJ * WF_PER_S * 2);    // + 184,320 B
    float* bfv = (float*)((char*)W1t + (size_t)5 * W1T_PER_NT * 2);   // + 73,728 B

    k_prep_w1<<<dim3(360), 256, 0, stream>>>(W1, W1t);
    k_fuse_b<<<dim3(NSUBJ), 256, 0, stream>>>(Ws, b1, bfv);
    k_fuse_w<<<dim3(5, 3, NSUBJ), 256, 0, stream>>>(Ws, W1t, Wf);
    k_main<<<dim3(TT / 64, BB), 256, 0, stream>>>(X, subj, Wf, bfv, out);
}

// Round 4
// 194.660 us; speedup vs baseline: 1.8595x; 1.8023x over previous
//
#include <hip/hip_runtime.h>

#define NSUBJ 64
#define CIN   295
#define DD    270
#define TT    2048
#define BB    128

// Wf tiled layout: [s][ks:10][kq:4][m:288][k8:8]  (bf16, c = ks*32+kq*8+k8)
// column c==295 holds the fused bias (Ws@b1); X[c==295] is synthesized as 1.0
#define WF_PER_S  92160   // 10*4*288*8
#define WF_PER_KS 9216    // 4*288*8
// W1t tiled layout: [ks:9][kq:4][c:320][8] bf16 (d = ks*32+kq*8+k8), c=295 -> b1
#define W1T_PER_KS 10240  // 4*320*8

typedef __attribute__((ext_vector_type(8))) short bf16x8;
typedef __attribute__((ext_vector_type(4))) float f32x4;
typedef unsigned short u16;

__device__ __forceinline__ u16 f2bf(float f) {
    union { float f; unsigned int u; } v; v.f = f;
    unsigned int r = v.u + 0x7FFFu + ((v.u >> 16) & 1u);  // RNE
    return (u16)(r >> 16);
}

__device__ __forceinline__ void glds16(const u16* g, u16* lds_base) {
    __builtin_amdgcn_global_load_lds(
        (const __attribute__((address_space(1))) unsigned int*)g,
        (__attribute__((address_space(3))) unsigned int*)lds_base, 16, 0, 0);
}

#define WAITV(N) asm volatile("s_waitcnt vmcnt(" #N ")" ::: "memory")
#define WAITL()  asm volatile("s_waitcnt lgkmcnt(0)" ::: "memory")
#define BAR()    __builtin_amdgcn_s_barrier()
#define SB()     __builtin_amdgcn_sched_barrier(0)

// ---------------------------------------------------------------------------
// W1 [270][295] f32 (+ b1 as c=295) -> W1t bf16 tiled [ks][kq][c:320][8]
// ---------------------------------------------------------------------------
__global__ __launch_bounds__(256) void k_prep_w1(const float* __restrict__ W1,
                                                 const float* __restrict__ b1,
                                                 u16* __restrict__ W1t)
{
    const int idx = blockIdx.x * 256 + threadIdx.x;      // 92160 total
    const int ks = idx / W1T_PER_KS;
    const int r  = idx - ks * W1T_PER_KS;
    const int kq = r / 2560;
    const int c  = (r - kq * 2560) >> 3;   // 0..319  (NOT &319 — 320 non-pow2)
    const int k8 = r & 7;
    const int d  = ks * 32 + kq * 8 + k8;
    float v = 0.f;
    if (d < DD) {
        if (c < CIN) v = W1[d * CIN + c];
        else if (c == CIN) v = b1[d];
    }
    W1t[idx] = f2bf(v);
}

// ---------------------------------------------------------------------------
// Wf[s] = bf16(Ws[s] @ [W1|b1]) in k_main's tiled A layout
// grid (3 mt, 64 s), block 256 = 4 waves (2M x 2N), tile 96e x 320c, K=288
// ---------------------------------------------------------------------------
__global__ __launch_bounds__(256, 1) void k_fuse_w(const float* __restrict__ Ws,
                                                   const u16* __restrict__ W1t,
                                                   u16* __restrict__ Wf)
{
    __shared__ u16 Aw[3072];    // [kq:4][96][8]
    __shared__ u16 Bw[10240];   // [kq:4][320][8]
    const int tid = threadIdx.x, lane = tid & 63, wid = tid >> 6;
    const int wm = wid >> 1, wn = wid & 1;
    const int mt = blockIdx.x, s = blockIdx.y;
    const int e0 = mt * 96;
    const float* Wsb = Ws + (size_t)s * DD * DD;

    f32x4 acc[3][10];
#pragma unroll
    for (int i = 0; i < 3; ++i)
#pragma unroll
        for (int j = 0; j < 10; ++j) acc[i][j] = (f32x4){0.f, 0.f, 0.f, 0.f};

    for (int ks = 0; ks < 9; ++ks) {
        const int k0 = ks * 32;
        // A stage: 96x32 f32 -> bf16
#pragma unroll
        for (int ci = 0; ci < 3; ++ci) {
            const int id = tid + ci * 256;
            const int m = id >> 3, q = id & 7;
            const int e = e0 + m, d = k0 + q * 4;
            float2 v01 = {0.f, 0.f}, v23 = {0.f, 0.f};
            if (e < DD) {
                if (d < DD)     v01 = *(const float2*)(Wsb + (size_t)e * DD + d);
                if (d + 2 < DD) v23 = *(const float2*)(Wsb + (size_t)e * DD + d + 2);
            }
            ushort4 h;
            h.x = f2bf(v01.x); h.y = f2bf(v01.y); h.z = f2bf(v23.x); h.w = f2bf(v23.y);
            *(ushort4*)(&Aw[(q >> 1) * 768 + m * 8 + (q & 1) * 4]) = h;
        }
        // B stage: 20KB contiguous, 5 glds per wave
#pragma unroll
        for (int k5 = 0; k5 < 5; ++k5) {
            const int seg = wid * 5 + k5;
            glds16(W1t + (size_t)ks * W1T_PER_KS + seg * 512 + lane * 8, &Bw[seg * 512]);
        }
        __syncthreads();
        bf16x8 af[3];
#pragma unroll
        for (int i = 0; i < 3; ++i)
            af[i] = *(const bf16x8*)(&Aw[(lane >> 4) * 768 + (wm * 48 + i * 16 + (lane & 15)) * 8]);
#pragma unroll
        for (int j = 0; j < 10; ++j) {
            const bf16x8 bfj = *(const bf16x8*)(&Bw[(lane >> 4) * 2560 + (wn * 160 + j * 16 + (lane & 15)) * 8]);
#pragma unroll
            for (int i = 0; i < 3; ++i)
                acc[i][j] = __builtin_amdgcn_mfma_f32_16x16x32_bf16(af[i], bfj, acc[i][j], 0, 0, 0);
        }
        __syncthreads();
    }
    const int rb = (lane >> 4) * 4, cc = lane & 15;
#pragma unroll
    for (int i = 0; i < 3; ++i) {
#pragma unroll
        for (int r = 0; r < 4; ++r) {
            const int e = e0 + wm * 48 + i * 16 + rb + r;
#pragma unroll
            for (int j = 0; j < 10; ++j) {
                const int c = wn * 160 + j * 16 + cc;
                Wf[(size_t)s * WF_PER_S + (c >> 5) * WF_PER_KS + ((c >> 3) & 3) * 2304
                   + e * 8 + (c & 7)] = f2bf(acc[i][j][r]);
            }
        }
    }
}

// ---------------------------------------------------------------------------
// out[b] = Wf[subj[b]] @ [X[b]; 1]
// grid (32 nt, 128 b), block 256 = 4 waves (2M x 2N), tile 288e x 64t, K=320
// Counted-vmcnt pipeline. Per wave per step: exactly 5 glds + 8 X loads,
// issue order pinned X(k) -> A(k) -> X(k+1) via sched_barrier(0).
// Steady-state queue at barrier: only next-tile X loads (8) in flight.
// ---------------------------------------------------------------------------
__global__ __launch_bounds__(256, 2) void k_main(const float* __restrict__ X,
                                                 const int* __restrict__ subj,
                                                 const u16* __restrict__ Wf,
                                                 float* __restrict__ out)
{
    __shared__ u16 Am[2][9216];   // [kq:4][288][8]
    __shared__ u16 Bm[2][2048];   // [kq:4][64][8]
    const int tid = threadIdx.x, lane = tid & 63, wid = tid >> 6;
    const int wm = wid >> 1, wn = wid & 1;
    const int nt = blockIdx.x, b = blockIdx.y;
    const int t0 = nt * 64;
    const int s = subj[b];
    const float* Xb = X + (size_t)b * CIN * TT;
    const u16* WfA = Wf + (size_t)s * WF_PER_S;
    const int bn = tid & 63, bkq = tid >> 6;

    f32x4 acc[9][2];
#pragma unroll
    for (int i = 0; i < 9; ++i)
#pragma unroll
        for (int j = 0; j < 2; ++j) acc[i][j] = (f32x4){0.f, 0.f, 0.f, 0.f};

    float xrE[8], xrO[8];

    // exactly 8 loads, distinct in-bounds addresses (CL: c-33 fallback, values
    // unused — WRITEB fixes up).  Distinct => no CSE => exact vmcnt counts.
#define LOADB(KS, XR, CL)                                                   \
    {                                                                       \
        _Pragma("unroll")                                                   \
        for (int q = 0; q < 8; ++q) {                                       \
            const int c = (KS) * 32 + bkq * 8 + q;                          \
            const int cl = ((CL) && c >= CIN) ? (c - 33) : c;               \
            XR[q] = Xb[(size_t)cl * TT + t0 + bn];                          \
        }                                                                   \
    }
#define WRITEB(KS, XR)                                                      \
    {                                                                       \
        bf16x8 h;                                                           \
        _Pragma("unroll")                                                   \
        for (int q = 0; q < 8; ++q) {                                       \
            const int c = (KS) * 32 + bkq * 8 + q;                          \
            u16 v = f2bf(XR[q]);                                            \
            if (c >= CIN) v = (c == CIN) ? (u16)0x3F80 : (u16)0;            \
            h[q] = (short)v;                                                \
        }                                                                   \
        *(bf16x8*)(&Bm[(KS) & 1][bkq * 512 + bn * 8]) = h;                  \
    }
    // 18 segs, wrapped so EVERY wave issues exactly 5 glds (segs 0,1 staged
    // twice by different waves — identical bytes, benign)
#define STAGEA(KS)                                                          \
    {                                                                       \
        _Pragma("unroll")                                                   \
        for (int k5 = 0; k5 < 5; ++k5) {                                    \
            int seg = wid * 5 + k5;                                         \
            if (seg >= 18) seg -= 18;                                       \
            glds16(WfA + (size_t)(KS) * WF_PER_KS + seg * 512 + lane * 8,   \
                   &Am[(KS) & 1][seg * 512]);                               \
        }                                                                   \
    }
#define COMPUTE(CUR)                                                        \
    {                                                                       \
        bf16x8 bfr[2];                                                      \
        _Pragma("unroll")                                                   \
        for (int j = 0; j < 2; ++j)                                         \
            bfr[j] = *(const bf16x8*)(&Bm[CUR][(lane >> 4) * 512 + (wn * 32 + j * 16 + (lane & 15)) * 8]); \
        _Pragma("unroll")                                                   \
        for (int i = 0; i < 9; ++i) {                                       \
            const bf16x8 af = *(const bf16x8*)(&Am[CUR][(lane >> 4) * 2304 + (wm * 144 + i * 16 + (lane & 15)) * 8]); \
            acc[i][0] = __builtin_amdgcn_mfma_f32_16x16x32_bf16(af, bfr[0], acc[i][0], 0, 0, 0); \
            acc[i][1] = __builtin_amdgcn_mfma_f32_16x16x32_bf16(af, bfr[1], acc[i][1], 0, 0, 0); \
        }                                                                   \
    }

    // ---- prologue: queue = [X0 x8, A0 x5, X1 x8] ----
    LOADB(0, xrE, 0); SB();
    STAGEA(0);        SB();
    LOADB(1, xrO, 0); SB();
    WAITV(13);                 // X0 retired
    WRITEB(0, xrE);
    WAITV(8);                  // A0 retired; X1 stays in flight across barrier
    WAITL(); BAR();

    // ---- steady steps; entry queue = [X(KS+1) x8] ----
#define STEP(KS, XLD, XWR, CL)                                              \
    {                                                                       \
        STAGEA((KS) + 1);        SB();                                      \
        LOADB((KS) + 2, XLD, CL); SB();                                     \
        COMPUTE((KS) & 1);                                                  \
        WAITV(13);             /* X(KS+1) retired */                        \
        WRITEB((KS) + 1, XWR);                                              \
        WAITV(8);              /* A(KS+1) retired; X(KS+2) in flight */     \
        WAITL(); BAR();                                                     \
    }
    for (int kk = 0; kk < 3; ++kk) {
        STEP(2 * kk,     xrE, xrO, 0);
        STEP(2 * kk + 1, xrO, xrE, 0);
    }
    STEP(6, xrE, xrO, 0);
    STEP(7, xrO, xrE, 1);      // LOADB(9) needs clamp (c up to 319)
    // ---- tail: entry queue = [X9 x8] ----
    STAGEA(9); SB();
    COMPUTE(0);
    WAITV(5);                  // X9 retired
    WRITEB(9, xrO);
    WAITV(0); WAITL(); BAR();
    COMPUTE(1);

    // epilogue: C/D layout col=lane&15, row=(lane>>4)*4+reg (bias fused in K)
    const int rb = (lane >> 4) * 4, cc = lane & 15;
#pragma unroll
    for (int i = 0; i < 9; ++i) {
#pragma unroll
        for (int r = 0; r < 4; ++r) {
            const int e = wm * 144 + i * 16 + rb + r;
            if (e < DD) {
#pragma unroll
                for (int j = 0; j < 2; ++j) {
                    const int t = t0 + wn * 32 + j * 16 + cc;
                    out[((size_t)b * DD + e) * TT + t] = acc[i][j][r];
                }
            }
        }
    }
#undef LOADB
#undef WRITEB
#undef STAGEA
#undef COMPUTE
#undef STEP
}

extern "C" void kernel_launch(void* const* d_in, const int* in_sizes, int n_in,
                              void* d_out, int out_size, void* d_ws, size_t ws_size,
                              hipStream_t stream) {
    const float* X    = (const float*)d_in[0];
    const int*   subj = (const int*)d_in[1];
    const float* W1   = (const float*)d_in[2];
    const float* b1   = (const float*)d_in[3];
    const float* Ws   = (const float*)d_in[4];
    float* out = (float*)d_out;

    u16* Wf  = (u16*)d_ws;                                         // 11,796,480 B
    u16* W1t = (u16*)((char*)d_ws + (size_t)NSUBJ * WF_PER_S * 2); // + 184,320 B

    k_prep_w1<<<dim3(360), 256, 0, stream>>>(W1, b1, W1t);
    k_fuse_w<<<dim3(3, NSUBJ), 256, 0, stream>>>(Ws, W1t, Wf);
    k_main<<<dim3(TT / 64, BB), 256, 0, stream>>>(X, subj, Wf, out);
}